// Round 7
// baseline (430.144 us; speedup 1.0000x reference)
//
#include <hip/hip_runtime.h>

// CombineEmbedder R10: 2-hop fused propagation. DEPTH=2 uses the SAME id_map in
// both passes, so out[r] is computable in ONE pass from x0: gather rows a,b=ids[r]
// plus ids[a], ids[b] (6 rows), evaluate the node matmul 4x (g0_r, g0_a, g0_b, g1)
// and reconstruct x1[a], x1[b] in-register with the exact two-pass bf16 rounding.
// Deletes: x1 write (64MB) + x1 re-read (64MB) + one launch boundary + one pass's
// fixed costs. MFMA was at 4% util -> the 2x extra matmuls are free.
// Ledger: bytes null (R5), occupancy null (R7), cache hints hurt (R8),
// ILP-pipelining hurt (R6), per-wave MLP x2 null (R9). This is the last
// mechanism-distinct lever: structural pass elimination.
// N=262144, FEAT=64, D=128, DEPTH=2.
//
// ws layout (bytes):
//   [0,      16384)  wembF  bf16 frags  (t*2+s)*64+lane (norm folded)
//   [16384,  49152)  wlF    bf16 frags  (t*4+s)*64+lane
//   [49152,  81920)  wnF    bf16 frags  (0.5 gather-mean folded)
//   [81920,  82432)  bembP  fp32[128]
//   [1 MB,   65 MB)  xbuf   bf16 [N][128] (x0 — phase_a output; prop2x input)
// NOTE: x0 no longer aliases d_out (prop2x reads x0 while writing fp32 out).

#define NROWS 262144
#define NBLK  4096

typedef __attribute__((ext_vector_type(8))) short bhalf8;
typedef __attribute__((ext_vector_type(4))) float f32x4;
typedef __attribute__((ext_vector_type(4))) unsigned int u32x4;

__device__ __forceinline__ unsigned short f2bf(float x) {
    union { float f; unsigned u; } v; v.f = x;
    unsigned r = v.u + 0x7FFFu + ((v.u >> 16) & 1u);   // RNE
    return (unsigned short)(r >> 16);
}
__device__ __forceinline__ float bflo(unsigned u) {
    union { unsigned u; float f; } v; v.u = u << 16; return v.f;
}
__device__ __forceinline__ float bfhi(unsigned u) {
    union { unsigned u; float f; } v; v.u = u & 0xFFFF0000u; return v.f;
}
__device__ __forceinline__ float bf2f(unsigned short s) {
    union { unsigned u; float f; } v; v.u = ((unsigned)s) << 16; return v.f;
}
__device__ __forceinline__ float leaky(float x) { return x >= 0.0f ? x : 0.01f * x; }

// ---------------- setup: pack weights to fragment-major bf16, fold norms ----------------
__global__ void __launch_bounds__(256)
setup_kernel(const float* __restrict__ smean, const float* __restrict__ sstd,
             const float* __restrict__ Wemb, const float* __restrict__ bemb,
             const float* __restrict__ Wl, const float* __restrict__ Wn,
             unsigned short* __restrict__ wpack, float* __restrict__ bembP)
{
    int task = blockIdx.x * 256 + threadIdx.x;
    if (blockIdx.x < 160) {
        if (task < 8192) {                       // wembF: frag=(t*2+s), K=64
            int f = task >> 9, idx = task & 511;
            int t = f >> 1, s = f & 1, lane = idx >> 3, j = idx & 7;
            int n = t * 16 + (lane & 15), k = s * 32 + (lane >> 4) * 8 + j;
            wpack[task] = f2bf(Wemb[k * 128 + n] / (sstd[k] + 0.001f));
        } else if (task < 24576) {               // wlF: frag=(t*4+s), K=128
            int u = task - 8192;
            int f = u >> 9, idx = u & 511;
            int t = f >> 2, s = f & 3, lane = idx >> 3, j = idx & 7;
            int n = t * 16 + (lane & 15), k = s * 32 + (lane >> 4) * 8 + j;
            wpack[task] = f2bf(Wl[k * 128 + n]);
        } else if (task < 40960) {               // wnF: 0.5 folded
            int u = task - 24576;
            int f = u >> 9, idx = u & 511;
            int t = f >> 2, s = f & 3, lane = idx >> 3, j = idx & 7;
            int n = t * 16 + (lane & 15), k = s * 32 + (lane >> 4) * 8 + j;
            wpack[task] = f2bf(0.5f * Wn[k * 128 + n]);
        }
    } else {                                     // bembP[n] = bemb[n] - sum_k mu_k/sig_k * Wemb[k][n]
        int n = threadIdx.x;
        if (n < 128) {
            float acc = bemb[n];
            for (int k = 0; k < 64; k++)
                acc -= smean[k] / (sstd[k] + 0.001f) * Wemb[k * 128 + n];
            bembP[n] = acc;
        }
    }
}

// ---------------- phase A: embed + residual layer + layernorm*0.5 ----------------
__global__ void __launch_bounds__(256, 4)
phase_a_kernel(const float* __restrict__ feats,
               const unsigned short* __restrict__ wembF,
               const float* __restrict__ bembP,
               const unsigned short* __restrict__ wlF,
               const float* __restrict__ bl,
               unsigned short* __restrict__ xout)
{
    __shared__ __align__(16) short hb[64 * 136];   // 17408 B
    const int tid = threadIdx.x, lane = tid & 63, wv = tid >> 6;
    const int m = lane & 15, q = lane >> 4;
    const int r0 = blockIdx.x * 64;

    const bhalf8* wbe = (const bhalf8*)wembF;
    const bhalf8* wbl = (const bhalf8*)wlF;

    // mm1 A-fragments straight from feats (norm folded into weights)
    bhalf8 af[2];
    #pragma unroll
    for (int s = 0; s < 2; s++) {
        const float* fp = feats + (size_t)(r0 + wv * 16 + m) * 64 + s * 32 + q * 8;
        f32x4 f0 = *(const f32x4*)fp;
        f32x4 f1 = *(const f32x4*)(fp + 4);
        bhalf8 a;
        #pragma unroll
        for (int jj = 0; jj < 4; jj++) { a[jj] = (short)f2bf(f0[jj]); a[4 + jj] = (short)f2bf(f1[jj]); }
        af[s] = a;
    }
    f32x4 acc[8] = {};
    #pragma unroll
    for (int s = 0; s < 2; s++)
        #pragma unroll
        for (int t = 0; t < 8; t++)
            acc[t] = __builtin_amdgcn_mfma_f32_16x16x32_bf16(af[s], wbe[(t * 2 + s) * 64 + lane], acc[t], 0, 0, 0);

    // h = leaky(acc + bembP): keep bf16-packed in regs for residual, bf16 to LDS for mm2-A
    unsigned hvp[8][2];
    #pragma unroll
    for (int t = 0; t < 8; t++) {
        float be = bembP[t * 16 + m];
        unsigned short hq[4];
        #pragma unroll
        for (int p = 0; p < 4; p++) {
            float h = leaky(acc[t][p] + be);
            hq[p] = f2bf(h);
            hb[(wv * 16 + q * 4 + p) * 136 + t * 16 + m] = (short)hq[p];
        }
        hvp[t][0] = (unsigned)hq[0] | ((unsigned)hq[1] << 16);
        hvp[t][1] = (unsigned)hq[2] | ((unsigned)hq[3] << 16);
    }
    // mm2: A from hb (own-tile, in-wave dep only), B from global frags
    f32x4 acc2[8] = {};
    #pragma unroll
    for (int s = 0; s < 4; s++) {
        bhalf8 a = *(const bhalf8*)&hb[(wv * 16 + m) * 136 + s * 32 + q * 8];
        #pragma unroll
        for (int t = 0; t < 8; t++)
            acc2[t] = __builtin_amdgcn_mfma_f32_16x16x32_bf16(a, wbl[(t * 4 + s) * 64 + lane], acc2[t], 0, 0, 0);
    }

    // v = leaky(leaky(acc2+bl)) + h ; layernorm ; *0.5
    float sum[4] = {0, 0, 0, 0}, ssq[4] = {0, 0, 0, 0};
    #pragma unroll
    for (int t = 0; t < 8; t++) {
        float bb = bl[t * 16 + m];
        float hvv[4] = { bflo(hvp[t][0]), bfhi(hvp[t][0]), bflo(hvp[t][1]), bfhi(hvp[t][1]) };
        #pragma unroll
        for (int p = 0; p < 4; p++) {
            float v = leaky(leaky(acc2[t][p] + bb)) + hvv[p];
            acc2[t][p] = v;                        // reuse accumulator regs as tv
            sum[p] += v; ssq[p] += v * v;
        }
    }
    #pragma unroll
    for (int p = 0; p < 4; p++) {
        #pragma unroll
        for (int d = 1; d < 16; d <<= 1) {
            sum[p] += __shfl_xor(sum[p], d, 64);
            ssq[p] += __shfl_xor(ssq[p], d, 64);
        }
    }
    #pragma unroll
    for (int p = 0; p < 4; p++) {
        float mu  = sum[p] * (1.0f / 128.0f);
        float var = ssq[p] * (1.0f / 128.0f) - mu * mu;
        float rs  = rsqrtf(var + 1e-5f) * 0.5f;
        int row = wv * 16 + q * 4 + p;
        #pragma unroll
        for (int t = 0; t < 8; t++)
            hb[row * 136 + t * 16 + m] = (short)f2bf((acc2[t][p] - mu) * rs);   // own-cell overwrite, safe
    }
    __syncthreads();
    for (int c = tid; c < 64 * 16; c += 256) {
        int row = c >> 4, cb = (c & 15) * 8;
        *reinterpret_cast<u32x4*>(&xout[(size_t)(r0 + row) * 128 + cb]) =
            *reinterpret_cast<const u32x4*>(&hb[row * 136 + cb]);
    }
}

// ---------------- prop helpers ----------------
__device__ __forceinline__ void gather_rows(const unsigned short* __restrict__ xin,
                                            int2 ids, int q, u32x4* ga, u32x4* gb)
{
    const unsigned short* xa = xin + (size_t)ids.x * 128 + q * 8;
    const unsigned short* xb = xin + (size_t)ids.y * 128 + q * 8;
    #pragma unroll
    for (int s = 0; s < 4; s++) {
        ga[s] = *(const u32x4*)(xa + s * 32);
        gb[s] = *(const u32x4*)(xb + s * 32);
    }
}

__device__ __forceinline__ void node_mm(const u32x4* ga, const u32x4* gb,
                                        const bhalf8* __restrict__ wbn, int lane, f32x4* acc)
{
    #pragma unroll
    for (int s = 0; s < 4; s++) {
        bhalf8 a;
        #pragma unroll
        for (int w = 0; w < 4; w++) {
            a[2 * w]     = (short)f2bf(bflo(ga[s][w]) + bflo(gb[s][w]));
            a[2 * w + 1] = (short)f2bf(bfhi(ga[s][w]) + bfhi(gb[s][w]));
        }
        #pragma unroll
        for (int t = 0; t < 8; t++)
            acc[t] = __builtin_amdgcn_mfma_f32_16x16x32_bf16(a, wbn[(t * 4 + s) * 64 + lane], acc[t], 0, 0, 0);
    }
}

__device__ __forceinline__ void stage_g(short* gls, const f32x4* acc,
                                        const float* __restrict__ bn, float scale,
                                        int wv, int q, int m)
{
    #pragma unroll
    for (int t = 0; t < 8; t++) {
        float bb = bn[t * 16 + m];
        #pragma unroll
        for (int p = 0; p < 4; p++)
            gls[(wv * 16 + q * 4 + p) * 136 + t * 16 + m] = (short)f2bf(leaky(acc[t][p] + bb) * scale);
    }
}

// ---------------- prop2x: fused DEPTH=2 propagation + heads ----------------
// Per output row r (ids fixed across depth):
//   x1[r] = bf16( x0[r] + gR ),  gR = leaky(Wn·(x0[a]+x0[b]) + bn)·scale   (0.5 in Wn)
//   x1[a] = bf16( x0[a] + gA ),  gA from ids[a]'s neighborhood; same for b
//   out[r] = f32(x1[r]) + leaky(Wn·bf16(f32(x1[a])+f32(x1[b])) + bn)·scale
// All bf16 roundings match the two-pass path bit-for-bit.
__global__ void __launch_bounds__(256)
prop2x_kernel(const unsigned short* __restrict__ xin, const int* __restrict__ idmap,
              const unsigned short* __restrict__ wnF, const float* __restrict__ bn,
              const float* __restrict__ rez, const float* __restrict__ Ww,
              const float* __restrict__ Wv, float* __restrict__ xout,
              float* __restrict__ wout, float* __restrict__ vout)
{
    __shared__ __align__(16) short T0[64 * 136];   // gA, then reused for g1
    __shared__ __align__(16) short T1[64 * 136];   // gB
    __shared__ __align__(16) short T2[64 * 136];   // gR
    const int tid = threadIdx.x, lane = tid & 63, wv = tid >> 6;
    const int m = lane & 15, q = lane >> 4;
    const int crow = tid >> 4, ccb = tid & 15;
    const int r0 = blockIdx.x * 64;
    const bhalf8* wbn = (const bhalf8*)wnF;
    const float scale = 0.25f * rez[0];

    // 1-hop ids, then dependent 2-hop ids
    const int myrow = r0 + wv * 16 + m;
    int2 ids  = ((const int2*)idmap)[myrow];
    int2 idsA = ((const int2*)idmap)[ids.x];
    int2 idsB = ((const int2*)idmap)[ids.y];

    // gather the 6-row neighborhood (A-frag lane mapping: row<-m, cols q*8+s*32)
    u32x4 ga[4], gb[4], gaa[4], gab[4], gba[4], gbb[4];
    gather_rows(xin, ids,  q, ga,  gb);
    gather_rows(xin, idsA, q, gaa, gab);
    gather_rows(xin, idsB, q, gba, gbb);

    // own rows for the final residual (coalesced)
    u32x4 xown[4];
    #pragma unroll
    for (int i = 0; i < 4; i++)
        xown[i] = *(const u32x4*)(xin + (size_t)(r0 + i * 16 + crow) * 128 + ccb * 8);

    // three pass-0 evaluations: gA (for x1[a]), gB (for x1[b]), gR (for x1[r])
    {
        f32x4 acc[8] = {};
        node_mm(gaa, gab, wbn, lane, acc);
        stage_g(T0, acc, bn, scale, wv, q, m);
    }
    {
        f32x4 acc[8] = {};
        node_mm(gba, gbb, wbn, lane, acc);
        stage_g(T1, acc, bn, scale, wv, q, m);
    }
    {
        f32x4 acc[8] = {};
        node_mm(ga, gb, wbn, lane, acc);
        stage_g(T2, acc, bn, scale, wv, q, m);
    }

    // reconstruct x1[a], x1[b] in A-frag layout (own-wave rows of T0/T1: same-wave
    // LDS program order, no barrier needed) and run the pass-1 matmul
    f32x4 acc1[8] = {};
    #pragma unroll
    for (int s = 0; s < 4; s++) {
        bhalf8 gAv = *(const bhalf8*)&T0[(wv * 16 + m) * 136 + s * 32 + q * 8];
        bhalf8 gBv = *(const bhalf8*)&T1[(wv * 16 + m) * 136 + s * 32 + q * 8];
        bhalf8 a1;
        #pragma unroll
        for (int w = 0; w < 4; w++) {
            // x1[a] = bf16(x0[a] + gA)  (bit-identical to pass-0 store)
            unsigned short xalo = f2bf(bflo(ga[s][w]) + bf2f((unsigned short)gAv[2 * w]));
            unsigned short xahi = f2bf(bfhi(ga[s][w]) + bf2f((unsigned short)gAv[2 * w + 1]));
            unsigned short xblo = f2bf(bflo(gb[s][w]) + bf2f((unsigned short)gBv[2 * w]));
            unsigned short xbhi = f2bf(bfhi(gb[s][w]) + bf2f((unsigned short)gBv[2 * w + 1]));
            // pass-1 A-frag = bf16(x1[a] + x1[b])  (0.5 folded in Wn)
            a1[2 * w]     = (short)f2bf(bf2f(xalo) + bf2f(xblo));
            a1[2 * w + 1] = (short)f2bf(bf2f(xahi) + bf2f(xbhi));
        }
        #pragma unroll
        for (int t = 0; t < 8; t++)
            acc1[t] = __builtin_amdgcn_mfma_f32_16x16x32_bf16(a1, wbn[(t * 4 + s) * 64 + lane], acc1[t], 0, 0, 0);
    }
    // stage g1 into T0 (own-wave rows; reads of T0 above are same-wave, in-order)
    stage_g(T0, acc1, bn, scale, wv, q, m);
    __syncthreads();

    // epilogue: x1[r] = bf16(x0[r]+gR); out = f32(x1[r]) + g1; heads
    #pragma unroll
    for (int i = 0; i < 4; i++) {
        int row = i * 16 + crow;
        u32x4 gR = *(const u32x4*)&T2[row * 136 + ccb * 8];
        u32x4 g1 = *(const u32x4*)&T0[row * 136 + ccb * 8];
        u32x4 xv = xown[i];
        float xn[8];
        #pragma unroll
        for (int w = 0; w < 4; w++) {
            unsigned short x1lo = f2bf(bflo(xv[w]) + bflo(gR[w]));
            unsigned short x1hi = f2bf(bfhi(xv[w]) + bfhi(gR[w]));
            xn[2 * w]     = bf2f(x1lo) + bflo(g1[w]);
            xn[2 * w + 1] = bf2f(x1hi) + bfhi(g1[w]);
        }
        float* op = xout + (size_t)(r0 + row) * 128 + ccb * 8;
        f32x4 o0, o1;
        #pragma unroll
        for (int w = 0; w < 4; w++) { o0[w] = xn[w]; o1[w] = xn[4 + w]; }
        *reinterpret_cast<f32x4*>(op)     = o0;
        *reinterpret_cast<f32x4*>(op + 4) = o1;
        f32x4 w0 = *(const f32x4*)&Ww[ccb * 8], w1 = *(const f32x4*)&Ww[ccb * 8 + 4];
        f32x4 v0 = *(const f32x4*)&Wv[ccb * 8], v1 = *(const f32x4*)&Wv[ccb * 8 + 4];
        float ws = 0.0f, vs = 0.0f;
        #pragma unroll
        for (int w = 0; w < 4; w++) {
            ws += xn[w] * w0[w] + xn[4 + w] * w1[w];
            vs += xn[w] * v0[w] + xn[4 + w] * v1[w];
        }
        #pragma unroll
        for (int d = 1; d < 16; d <<= 1) {
            ws += __shfl_xor(ws, d, 64);
            vs += __shfl_xor(vs, d, 64);
        }
        if ((lane & 15) == 0) { wout[r0 + row] = ws; vout[r0 + row] = vs; }
    }
}

extern "C" void kernel_launch(void* const* d_in, const int* in_sizes, int n_in,
                              void* d_out, int out_size, void* d_ws, size_t ws_size,
                              hipStream_t stream) {
    const float* feats = (const float*)d_in[0];
    const int*   idmap = (const int*)d_in[2];
    const float* smean = (const float*)d_in[3];
    const float* sstd  = (const float*)d_in[4];
    const float* Wemb  = (const float*)d_in[5];
    const float* bemb  = (const float*)d_in[6];
    const float* Wl    = (const float*)d_in[7];
    const float* bl    = (const float*)d_in[8];
    const float* Wn    = (const float*)d_in[9];
    const float* bn    = (const float*)d_in[10];
    const float* rez   = (const float*)d_in[11];
    const float* Ww    = (const float*)d_in[12];
    const float* Wv    = (const float*)d_in[13];

    char* ws = (char*)d_ws;
    unsigned short* wpack = (unsigned short*)ws;          // wembF @0, wlF @8192, wnF @24576 (shorts)
    float*          bembP = (float*)(ws + 81920);
    unsigned short* xbuf  = (unsigned short*)(ws + (1ull << 20));   // x0 (bf16)

    float* out = (float*)d_out;
    float* wout = out + (size_t)NROWS * 128;
    float* vout = wout + NROWS;

    setup_kernel<<<161, 256, 0, stream>>>(smean, sstd, Wemb, bemb, Wl, Wn, wpack, bembP);
    phase_a_kernel<<<NBLK, 256, 0, stream>>>(feats, wpack, bembP, wpack + 8192, bl, xbuf);
    prop2x_kernel<<<NBLK, 256, 0, stream>>>(xbuf, idmap, wpack + 24576, bn, rez, Ww, Wv,
                                            out, wout, vout);
}

// Round 8
// 344.651 us; speedup vs baseline: 1.2481x; 1.2481x over previous
//
#include <hip/hip_runtime.h>

// CombineEmbedder R11 = exact revert to R4, the best-measured kernel (344.95 /
// 344.28 us across two runs). Seven-round ledger, all mechanism-distinct levers
// measured against it: gather-byte reduction null (R5, L3-resident), persistent
// -block ILP pipelining -96us (R6), 2x occupancy null (R7), VGPR caps hurt (R7),
// nt-load/store hurt (R8), per-wave MLP x2 null (R9 A/B), 2-hop pass fusion
// +51us (R10: 6-row neighborhood defeats L3 reuse, 52KB LDS -> 11.6% occupancy,
// dependent idmap chain). Residual ~3x-over-stream-floor is a wave-lifetime
// latency floor common to all variants; not addressable at HIP source level
// with the evidence available. Fragment-major pre-packed bf16 weights (setup
// kernel), B operands + mm1-A loaded global->VGPR directly, gather->registers,
// residual/heads fused into coalesced copy-out.
// N=262144, FEAT=64, D=128, DEPTH=2.
//
// ws layout (bytes):
//   [0,      16384)  wembF  bf16 frags  (t*2+s)*64+lane, 8 shorts each (norm folded)
//   [16384,  49152)  wlF    bf16 frags  (t*4+s)*64+lane
//   [49152,  81920)  wnF    bf16 frags  (0.5 gather-mean folded)
//   [81920,  82432)  bembP  fp32[128]   (bemb - (mu/sigma) @ Wemb)
//   [1 MB,   65 MB)  x1     bf16 [N][128] ping buffer
// x0 (bf16) aliases d_out's x_main region (dead before final fp32 write).

#define NROWS 262144
#define NBLK  4096

typedef __attribute__((ext_vector_type(8))) short bhalf8;
typedef __attribute__((ext_vector_type(4))) float f32x4;
typedef __attribute__((ext_vector_type(4))) unsigned int u32x4;

__device__ __forceinline__ unsigned short f2bf(float x) {
    union { float f; unsigned u; } v; v.f = x;
    unsigned r = v.u + 0x7FFFu + ((v.u >> 16) & 1u);   // RNE
    return (unsigned short)(r >> 16);
}
__device__ __forceinline__ float bflo(unsigned u) {
    union { unsigned u; float f; } v; v.u = u << 16; return v.f;
}
__device__ __forceinline__ float bfhi(unsigned u) {
    union { unsigned u; float f; } v; v.u = u & 0xFFFF0000u; return v.f;
}
__device__ __forceinline__ float leaky(float x) { return x >= 0.0f ? x : 0.01f * x; }

// ---------------- setup: pack weights to fragment-major bf16, fold norms ----------------
__global__ void __launch_bounds__(256)
setup_kernel(const float* __restrict__ smean, const float* __restrict__ sstd,
             const float* __restrict__ Wemb, const float* __restrict__ bemb,
             const float* __restrict__ Wl, const float* __restrict__ Wn,
             unsigned short* __restrict__ wpack, float* __restrict__ bembP)
{
    int task = blockIdx.x * 256 + threadIdx.x;
    if (blockIdx.x < 160) {
        if (task < 8192) {                       // wembF: frag=(t*2+s), K=64
            int f = task >> 9, idx = task & 511;
            int t = f >> 1, s = f & 1, lane = idx >> 3, j = idx & 7;
            int n = t * 16 + (lane & 15), k = s * 32 + (lane >> 4) * 8 + j;
            wpack[task] = f2bf(Wemb[k * 128 + n] / (sstd[k] + 0.001f));
        } else if (task < 24576) {               // wlF: frag=(t*4+s), K=128
            int u = task - 8192;
            int f = u >> 9, idx = u & 511;
            int t = f >> 2, s = f & 3, lane = idx >> 3, j = idx & 7;
            int n = t * 16 + (lane & 15), k = s * 32 + (lane >> 4) * 8 + j;
            wpack[task] = f2bf(Wl[k * 128 + n]);
        } else if (task < 40960) {               // wnF: 0.5 folded
            int u = task - 24576;
            int f = u >> 9, idx = u & 511;
            int t = f >> 2, s = f & 3, lane = idx >> 3, j = idx & 7;
            int n = t * 16 + (lane & 15), k = s * 32 + (lane >> 4) * 8 + j;
            wpack[task] = f2bf(0.5f * Wn[k * 128 + n]);
        }
    } else {                                     // bembP[n] = bemb[n] - sum_k mu_k/sig_k * Wemb[k][n]
        int n = threadIdx.x;
        if (n < 128) {
            float acc = bemb[n];
            for (int k = 0; k < 64; k++)
                acc -= smean[k] / (sstd[k] + 0.001f) * Wemb[k * 128 + n];
            bembP[n] = acc;
        }
    }
}

// ---------------- phase A: embed + residual layer + layernorm*0.5 ----------------
__global__ void __launch_bounds__(256)
phase_a_kernel(const float* __restrict__ feats,
               const unsigned short* __restrict__ wembF,
               const float* __restrict__ bembP,
               const unsigned short* __restrict__ wlF,
               const float* __restrict__ bl,
               unsigned short* __restrict__ xout)
{
    __shared__ __align__(16) short hb[64 * 136];   // 17408 B
    const int tid = threadIdx.x, lane = tid & 63, wv = tid >> 6;
    const int m = lane & 15, q = lane >> 4;
    const int r0 = blockIdx.x * 64;

    const bhalf8* wbe = (const bhalf8*)wembF;
    const bhalf8* wbl = (const bhalf8*)wlF;

    // mm1 A-fragments straight from feats (norm folded into weights)
    bhalf8 af[2];
    #pragma unroll
    for (int s = 0; s < 2; s++) {
        const float* fp = feats + (size_t)(r0 + wv * 16 + m) * 64 + s * 32 + q * 8;
        f32x4 f0 = *(const f32x4*)fp;
        f32x4 f1 = *(const f32x4*)(fp + 4);
        bhalf8 a;
        #pragma unroll
        for (int jj = 0; jj < 4; jj++) { a[jj] = (short)f2bf(f0[jj]); a[4 + jj] = (short)f2bf(f1[jj]); }
        af[s] = a;
    }
    f32x4 acc[8] = {};
    #pragma unroll
    for (int s = 0; s < 2; s++)
        #pragma unroll
        for (int t = 0; t < 8; t++)
            acc[t] = __builtin_amdgcn_mfma_f32_16x16x32_bf16(af[s], wbe[(t * 2 + s) * 64 + lane], acc[t], 0, 0, 0);

    // h = leaky(acc + bembP): keep fp32 in regs for residual, bf16 to LDS for mm2-A
    float hv[8][4];
    #pragma unroll
    for (int t = 0; t < 8; t++) {
        float be = bembP[t * 16 + m];
        #pragma unroll
        for (int p = 0; p < 4; p++) {
            float h = leaky(acc[t][p] + be);
            hv[t][p] = h;
            hb[(wv * 16 + q * 4 + p) * 136 + t * 16 + m] = (short)f2bf(h);
        }
    }
    // mm2: A from hb (own-tile, in-wave dep only), B from global frags
    f32x4 acc2[8] = {};
    #pragma unroll
    for (int s = 0; s < 4; s++) {
        bhalf8 a = *(const bhalf8*)&hb[(wv * 16 + m) * 136 + s * 32 + q * 8];
        #pragma unroll
        for (int t = 0; t < 8; t++)
            acc2[t] = __builtin_amdgcn_mfma_f32_16x16x32_bf16(a, wbl[(t * 4 + s) * 64 + lane], acc2[t], 0, 0, 0);
    }

    // t = leaky(leaky(acc2+bl)) + h ; layernorm ; *0.5
    float tv[8][4];
    float sum[4] = {0, 0, 0, 0}, ssq[4] = {0, 0, 0, 0};
    #pragma unroll
    for (int t = 0; t < 8; t++) {
        float bb = bl[t * 16 + m];
        #pragma unroll
        for (int p = 0; p < 4; p++) {
            float v = leaky(leaky(acc2[t][p] + bb)) + hv[t][p];
            tv[t][p] = v;
            sum[p] += v; ssq[p] += v * v;
        }
    }
    #pragma unroll
    for (int p = 0; p < 4; p++) {
        #pragma unroll
        for (int d = 1; d < 16; d <<= 1) {
            sum[p] += __shfl_xor(sum[p], d, 64);
            ssq[p] += __shfl_xor(ssq[p], d, 64);
        }
    }
    #pragma unroll
    for (int p = 0; p < 4; p++) {
        float mu  = sum[p] * (1.0f / 128.0f);
        float var = ssq[p] * (1.0f / 128.0f) - mu * mu;
        float rs  = rsqrtf(var + 1e-5f) * 0.5f;
        int row = wv * 16 + q * 4 + p;
        #pragma unroll
        for (int t = 0; t < 8; t++)
            hb[row * 136 + t * 16 + m] = (short)f2bf((tv[t][p] - mu) * rs);   // own-tile overwrite, safe
    }
    __syncthreads();
    for (int c = tid; c < 64 * 16; c += 256) {
        int row = c >> 4, cb = (c & 15) * 8;
        *reinterpret_cast<u32x4*>(&xout[(size_t)(r0 + row) * 128 + cb]) =
            *reinterpret_cast<const u32x4*>(&hb[row * 136 + cb]);
    }
}

// ---------------- prop: gather(+) -> node matmul -> rezero residual (+heads) ----------------
template <typename TOUT>
__global__ void __launch_bounds__(256)
prop_kernel(const unsigned short* __restrict__ xin, const int* __restrict__ idmap,
            const unsigned short* __restrict__ wnF, const float* __restrict__ bn,
            const float* __restrict__ rez, const float* __restrict__ Ww,
            const float* __restrict__ Wv, TOUT* __restrict__ xout,
            float* __restrict__ wout, float* __restrict__ vout, int final_pass)
{
    __shared__ __align__(16) short gls[64 * 136];
    const int tid = threadIdx.x, lane = tid & 63, wv = tid >> 6;
    const int m = lane & 15, q = lane >> 4;
    const int r0 = blockIdx.x * 64;
    const bhalf8* wbn = (const bhalf8*)wnF;

    // gather two rows straight into A-fragments (0.5 folded into Wn)
    const int myrow = r0 + wv * 16 + m;
    int2 ids = ((const int2*)idmap)[myrow];
    const unsigned short* xa = xin + (size_t)ids.x * 128;
    const unsigned short* xb = xin + (size_t)ids.y * 128;
    bhalf8 afr[4];
    #pragma unroll
    for (int s = 0; s < 4; s++) {
        u32x4 ua = *(const u32x4*)(xa + s * 32 + q * 8);
        u32x4 ub = *(const u32x4*)(xb + s * 32 + q * 8);
        bhalf8 o;
        #pragma unroll
        for (int w = 0; w < 4; w++) {
            float lo = bflo(ua[w]) + bflo(ub[w]);
            float hi = bfhi(ua[w]) + bfhi(ub[w]);
            o[2 * w]     = (short)f2bf(lo);
            o[2 * w + 1] = (short)f2bf(hi);
        }
        afr[s] = o;
    }

    f32x4 acc[8] = {};
    #pragma unroll
    for (int s = 0; s < 4; s++)
        #pragma unroll
        for (int t = 0; t < 8; t++)
            acc[t] = __builtin_amdgcn_mfma_f32_16x16x32_bf16(afr[s], wbn[(t * 4 + s) * 64 + lane], acc[t], 0, 0, 0);

    // stage g*scale (bf16) in C-layout
    const float scale = 0.25f * rez[0];
    #pragma unroll
    for (int t = 0; t < 8; t++) {
        float bb = bn[t * 16 + m];
        #pragma unroll
        for (int p = 0; p < 4; p++)
            gls[(wv * 16 + q * 4 + p) * 136 + t * 16 + m] = (short)f2bf(leaky(acc[t][p] + bb) * scale);
    }
    __syncthreads();

    // fused copy-out: xn = x_old + g*scale (coalesced), + heads on final pass
    #pragma unroll
    for (int i = 0; i < 4; i++) {
        int task = i * 256 + tid;
        int row = task >> 4, cb = task & 15;
        u32x4 gv = *(const u32x4*)&gls[row * 136 + cb * 8];
        u32x4 xv = *(const u32x4*)(xin + (size_t)(r0 + row) * 128 + cb * 8);
        float xn[8];
        #pragma unroll
        for (int w = 0; w < 4; w++) {
            xn[2 * w]     = bflo(xv[w]) + bflo(gv[w]);
            xn[2 * w + 1] = bfhi(xv[w]) + bfhi(gv[w]);
        }
        if (!final_pass) {
            u32x4 ov;
            #pragma unroll
            for (int w = 0; w < 4; w++)
                ov[w] = (unsigned)f2bf(xn[2 * w]) | ((unsigned)f2bf(xn[2 * w + 1]) << 16);
            *reinterpret_cast<u32x4*>(reinterpret_cast<unsigned short*>(xout) + (size_t)(r0 + row) * 128 + cb * 8) = ov;
        } else {
            float* op = reinterpret_cast<float*>(xout) + (size_t)(r0 + row) * 128 + cb * 8;
            f32x4 o0, o1;
            #pragma unroll
            for (int w = 0; w < 4; w++) { o0[w] = xn[w]; o1[w] = xn[4 + w]; }
            *reinterpret_cast<f32x4*>(op)     = o0;
            *reinterpret_cast<f32x4*>(op + 4) = o1;
            f32x4 w0 = *(const f32x4*)&Ww[cb * 8], w1 = *(const f32x4*)&Ww[cb * 8 + 4];
            f32x4 v0 = *(const f32x4*)&Wv[cb * 8], v1 = *(const f32x4*)&Wv[cb * 8 + 4];
            float ws = 0.0f, vs = 0.0f;
            #pragma unroll
            for (int w = 0; w < 4; w++) {
                ws += xn[w] * w0[w] + xn[4 + w] * w1[w];
                vs += xn[w] * v0[w] + xn[4 + w] * v1[w];
            }
            #pragma unroll
            for (int d = 1; d < 16; d <<= 1) {
                ws += __shfl_xor(ws, d, 64);
                vs += __shfl_xor(vs, d, 64);
            }
            if ((lane & 15) == 0) { wout[r0 + row] = ws; vout[r0 + row] = vs; }
        }
    }
}

extern "C" void kernel_launch(void* const* d_in, const int* in_sizes, int n_in,
                              void* d_out, int out_size, void* d_ws, size_t ws_size,
                              hipStream_t stream) {
    const float* feats = (const float*)d_in[0];
    const int*   idmap = (const int*)d_in[2];
    const float* smean = (const float*)d_in[3];
    const float* sstd  = (const float*)d_in[4];
    const float* Wemb  = (const float*)d_in[5];
    const float* bemb  = (const float*)d_in[6];
    const float* Wl    = (const float*)d_in[7];
    const float* bl    = (const float*)d_in[8];
    const float* Wn    = (const float*)d_in[9];
    const float* bn    = (const float*)d_in[10];
    const float* rez   = (const float*)d_in[11];
    const float* Ww    = (const float*)d_in[12];
    const float* Wv    = (const float*)d_in[13];

    char* ws = (char*)d_ws;
    unsigned short* wpack = (unsigned short*)ws;          // wembF @0, wlF @8192, wnF @24576 (shorts)
    float*          bembP = (float*)(ws + 81920);
    unsigned short* x1    = (unsigned short*)(ws + (1 << 20));

    float* out = (float*)d_out;
    unsigned short* x0 = (unsigned short*)d_out;          // bf16 scratch in x_main region
    float* wout = out + (size_t)NROWS * 128;
    float* vout = wout + NROWS;

    setup_kernel<<<161, 256, 0, stream>>>(smean, sstd, Wemb, bemb, Wl, Wn, wpack, bembP);
    phase_a_kernel<<<NBLK, 256, 0, stream>>>(feats, wpack, bembP, wpack + 8192, bl, x0);
    prop_kernel<unsigned short><<<NBLK, 256, 0, stream>>>(x0, idmap, wpack + 24576, bn, rez, Ww, Wv,
                                                          x1, nullptr, nullptr, 0);
    prop_kernel<float><<<NBLK, 256, 0, stream>>>(x1, idmap, wpack + 24576, bn, rez, Ww, Wv,
                                                 out, wout, vout, 1);
}